// Round 1
// baseline (365.232 us; speedup 1.0000x reference)
//
#include <hip/hip_runtime.h>

// Winograd F(2x2,3x3) with fixed Laplacian filter.
// Per tile: D = B x B^T ; Y = F .* D ; O = A Y A^T  (F precomputed below).
//
// F = G @ FILT @ G^T =
//   [[ 0.0, -0.5,  0.5,  0.0],
//    [-0.5,  0.0, -1.0, -0.5],
//    [ 0.5, -1.0,  2.0,  0.5],
//    [ 0.0, -0.5,  0.5,  0.0]]
//
// Memory-bound: 80 B/tile, ~70 flops/tile. Target ~53 us at 6.3 TB/s.

__global__ __launch_bounds__(256) void winograd_tile_kernel(
    const float4* __restrict__ x4,   // [n_tiles*4] rows of 4 floats
    float4* __restrict__ out4,       // [n_tiles] (2x2 output per tile)
    int n_tiles)
{
    int t = blockIdx.x * blockDim.x + threadIdx.x;
    if (t >= n_tiles) return;

    // Load the 4x4 tile: one 64B cache line per tile, 16B per load.
    float4 r0 = x4[4 * t + 0];
    float4 r1 = x4[4 * t + 1];
    float4 r2 = x4[4 * t + 2];
    float4 r3 = x4[4 * t + 3];

    float xin[4][4] = {
        {r0.x, r0.y, r0.z, r0.w},
        {r1.x, r1.y, r1.z, r1.w},
        {r2.x, r2.y, r2.z, r2.w},
        {r3.x, r3.y, r3.z, r3.w},
    };

    // Bx = B @ x  (row combinations; B = [[1,0,-1,0],[0,1,1,0],[0,-1,1,0],[0,1,0,-1]])
    float bx[4][4];
#pragma unroll
    for (int c = 0; c < 4; ++c) {
        bx[0][c] = xin[0][c] - xin[2][c];
        bx[1][c] = xin[1][c] + xin[2][c];
        bx[2][c] = xin[2][c] - xin[1][c];
        bx[3][c] = xin[1][c] - xin[3][c];
    }

    // D = Bx @ B^T  (same combination applied to columns)
    float D[4][4];
#pragma unroll
    for (int r = 0; r < 4; ++r) {
        D[r][0] = bx[r][0] - bx[r][2];
        D[r][1] = bx[r][1] + bx[r][2];
        D[r][2] = bx[r][2] - bx[r][1];
        D[r][3] = bx[r][1] - bx[r][3];
    }

    // Y = F .* D  (corners of F are zero)
    float Y[4][4];
    Y[0][0] = 0.0f;
    Y[0][1] = -0.5f * D[0][1];
    Y[0][2] =  0.5f * D[0][2];
    Y[0][3] = 0.0f;
    Y[1][0] = -0.5f * D[1][0];
    Y[1][1] = 0.0f;
    Y[1][2] = -1.0f * D[1][2];
    Y[1][3] = -0.5f * D[1][3];
    Y[2][0] =  0.5f * D[2][0];
    Y[2][1] = -1.0f * D[2][1];
    Y[2][2] =  2.0f * D[2][2];
    Y[2][3] =  0.5f * D[2][3];
    Y[3][0] = 0.0f;
    Y[3][1] = -0.5f * D[3][1];
    Y[3][2] =  0.5f * D[3][2];
    Y[3][3] = 0.0f;

    // AY = A @ Y  (A = [[1,1,1,0],[0,1,-1,-1]])
    float ay0[4], ay1[4];
#pragma unroll
    for (int c = 0; c < 4; ++c) {
        ay0[c] = Y[0][c] + Y[1][c] + Y[2][c];
        ay1[c] = Y[1][c] - Y[2][c] - Y[3][c];
    }

    // O = AY @ A^T  -> 2x2
    float4 o;
    o.x = ay0[0] + ay0[1] + ay0[2];   // O[0][0]
    o.y = ay0[1] - ay0[2] - ay0[3];   // O[0][1]
    o.z = ay1[0] + ay1[1] + ay1[2];   // O[1][0]
    o.w = ay1[1] - ay1[2] - ay1[3];   // O[1][1]

    out4[t] = o;
}

extern "C" void kernel_launch(void* const* d_in, const int* in_sizes, int n_in,
                              void* d_out, int out_size, void* d_ws, size_t ws_size,
                              hipStream_t stream)
{
    const float4* x4 = (const float4*)d_in[0];
    float4* out4 = (float4*)d_out;
    int n_tiles = in_sizes[0] / 16;

    int block = 256;
    int grid = (n_tiles + block - 1) / block;
    winograd_tile_kernel<<<grid, block, 0, stream>>>(x4, out4, n_tiles);
}